// Round 3
// baseline (108.938 us; speedup 1.0000x reference)
//
#include <hip/hip_runtime.h>

// Problem constants (fixed by reference)
constexpr int N_AG = 4096;   // N agents
constexpr int M_CL = 256;    // M clusters
constexpr int KD   = 32;     // K dim
constexpr float WEPS = 1e-6f;

// ws layout (floats)
constexpr int PART_STRIDE = 1088;                 // [P(1024, MFMA-lane layout) | S1(32) | Z | count | pad]
constexpr int PART_SZ = M_CL * 4 * PART_STRIDE;   // 1,114,112
constexpr int VT_OFF  = PART_SZ;                  // vT (32 x 4096) k-major
constexpr int WT_OFF  = VT_OFF + N_AG * KD;       // Wt (256 x 4096) masked

typedef __attribute__((ext_vector_type(8))) short short8;   // 8 bf16 (4 VGPRs)
typedef __attribute__((ext_vector_type(4))) float f32x4;

__device__ __forceinline__ float rlane(float x, int l) {
    return __int_as_float(__builtin_amdgcn_readlane(__float_as_int(x), l));
}

__device__ __forceinline__ float fast_rcp(float x) {
#if __has_builtin(__builtin_amdgcn_rcpf)
    float r = __builtin_amdgcn_rcpf(x);      // v_rcp_f32 (~1 ulp)
    return r * (2.0f - x * r);               // +1 NR step -> ~2^-29 rel err
#else
    return 1.0f / x;
#endif
}

// ---------------------------------------------------------------------------
// ROUND-9 solve: row-layout forward elimination + back-substitution.
// Replaces full Gauss-Jordan (2370 VALU ops/wave: eliminates above AND below
// the pivot) with LU-style solve (~1450 ops): forward updates only j>J rows,
// back-sub is 4 ops/step since x_j = rlane(rhs,J)*rlane(pl,J) is uniform.
// Lane r (r = lane&31; lanes 32-63 duplicate rows 0-31 so broadcasts stay
// readlane-uniform with zero divergence) holds row r of A + rhs scalar.
// No pivoting: SPD with diag >= 1 (same assumption the passing GJ made).
// Template-recursive so all a[j] indices are compile-time (R6 scratch lesson).
// ---------------------------------------------------------------------------
template<int J>
struct FE {
    static __device__ __forceinline__ void run(float (&a)[32], float& rhs,
                                               float& pl, const int rr) {
        const float piv  = rlane(a[J], J);
        const float pinv = fast_rcp(piv);
        if (rr == J) pl = pinv;                       // save for back-sub
        const float f = (rr > J) ? a[J] * pinv : 0.0f; // rows <= J frozen
        #pragma unroll
        for (int j = J + 1; j < 32; ++j) {
            const float rJ = rlane(a[j], J);
            a[j] = fmaf(-f, rJ, a[j]);
        }
        const float rb = rlane(rhs, J);
        rhs = fmaf(-f, rb, rhs);
        FE<J + 1>::run(a, rhs, pl, rr);
    }
};
template<> struct FE<32> {
    static __device__ __forceinline__ void run(float (&)[32], float&, float&, const int) {}
};

template<int J>
struct BS {
    static __device__ __forceinline__ void run(const float (&a)[32], float& rhs,
                                               const float pl, float& xv, const int rr) {
        const float xj = rlane(rhs, J) * rlane(pl, J);  // uniform
        if (rr == J) xv = xj;
        rhs = fmaf(-a[J], xj, rhs);   // corrupts rr>=J lanes: already consumed
        BS<J - 1>::run(a, rhs, pl, xv, rr);
    }
};
template<> struct BS<-1> {
    static __device__ __forceinline__ void run(const float (&)[32], float&,
                                               const float, float&, const int) {}
};

// ---------------------------------------------------------------------------
// K1 prep:
//  blocks 0..1023:    masked W (4096x256) -> Wt (256x4096)   [independent of solve]
//  blocks 1024..2047: 32x32 SPD solve (4 matrices/block, 1 wave each), then
//                     in-block LDS transpose -> write vT (32x4096) directly.
// ---------------------------------------------------------------------------
__global__ __launch_bounds__(256) void prep_kernel(const float* __restrict__ W,
                                                   const float* __restrict__ mu,
                                                   const float* __restrict__ oc,
                                                   float* __restrict__ ws) {
    __shared__ float tb[32][33];
    __shared__ float sv[4][32];
    const int bid = blockIdx.x;
    const int t   = threadIdx.x;

    if (bid < 1024) {
        // ---- masked W transpose tile ----
        const int x = t & 31;
        const int y = t >> 5;                 // 0..7
        const int n0 = (bid & 127) * 32;
        const int m0 = (bid >> 7) * 32;
        float* Wt = ws + WT_OFF;
        #pragma unroll
        for (int r = 0; r < 4; ++r) {
            const int n = y + 8 * r;
            float w = W[(size_t)(n0 + n) * 256 + m0 + x];
            tb[n][x] = (w >= WEPS) ? w : 0.0f;
        }
        __syncthreads();
        #pragma unroll
        for (int r = 0; r < 4; ++r) {
            const int mm = y + 8 * r;
            Wt[(size_t)(m0 + mm) * 4096 + n0 + x] = tb[x][mm];
        }
    } else {
        // ---- batched solve: wave w owns matrix; lane rr owns row rr ----
        const int lane = t & 63;
        const int wid  = t >> 6;
        const int n0   = (bid - 1024) * 4;
        const int idx  = n0 + wid;
        const int rr   = lane & 31;           // lanes 32-63 mirror rows 0-31

        float a[32];
        const float4* src = reinterpret_cast<const float4*>(oc + (size_t)idx * 1024 + rr * 32);
        #pragma unroll
        for (int q = 0; q < 8; ++q) {
            const float4 t4 = src[q];
            a[4 * q + 0] = t4.x; a[4 * q + 1] = t4.y;
            a[4 * q + 2] = t4.z; a[4 * q + 3] = t4.w;
        }
        float rhs = mu[(size_t)idx * 32 + rr];
        float pl = 0.0f, xv = 0.0f;

        FE<0>::run(a, rhs, pl, rr);
        BS<31>::run(a, rhs, pl, xv, rr);

        if (lane < 32) sv[wid][lane] = xv;
        __syncthreads();
        // vT[k][n0..n0+3]: 16B-coalesced per k-row
        if (t < 128) {
            const int k = t >> 2;
            const int j = t & 3;
            ws[VT_OFF + (size_t)k * 4096 + n0 + j] = sv[j][k];
        }
    }
}

// ---------------------------------------------------------------------------
// K2: per (m,p) block, S2 = sum_n w v v^T via u = sqrt(w) v, MFMA
// rank-reduction over n. u split hi/lo bf16 (RTZ).
// Epilogue stores P = hh + 2*hl in MFMA-native lane layout (G symmetric ->
// tr(G(hl+hl^T)) = 2 tr(G hl)); bank = lane&31 -> 2-way conflict = free.
// zred/s1buf overlaid on swbuf (dead after main loop) -> LDS 40,960 B
// -> 4 blocks/CU, grid exactly 4x256.
// ---------------------------------------------------------------------------
__global__ __launch_bounds__(256, 4) void partial_kernel(const float* __restrict__ Wt,
                                                         const float* __restrict__ vT,
                                                         float* __restrict__ wsout) {
    const int m = blockIdx.x >> 2;
    const int p = blockIdx.x & 3;
    const int t = threadIdx.x;
    const int lane = t & 63;
    const int wv   = t >> 6;     // wave id 0..3

    __shared__ unsigned ubuf[4][2][32 * 36];  // [wave][hi/lo][k*36 + n/2] : 36,864 B
    __shared__ float swbuf[1024];             // sqrt(w); dead after main loop: 4,096 B
    float* const s1buf = swbuf;               // overlay [0..31]
    float* const zred  = swbuf + 32;          // overlay [32..39]

    // ---- stage w: sqrt, Z, count (swbuf region is wave-private: no barrier) ----
    const float4 wv4 = reinterpret_cast<const float4*>(Wt + (size_t)m * 4096 + p * 1024)[t];
    float zacc = wv4.x + wv4.y + wv4.z + wv4.w;
    float cacc = (wv4.x >= WEPS ? 1.f : 0.f) + (wv4.y >= WEPS ? 1.f : 0.f)
               + (wv4.z >= WEPS ? 1.f : 0.f) + (wv4.w >= WEPS ? 1.f : 0.f);
    reinterpret_cast<float4*>(swbuf)[t] =
        make_float4(sqrtf(wv4.x), sqrtf(wv4.y), sqrtf(wv4.z), sqrtf(wv4.w));

    f32x4 Chh[4], Chl[4];
    #pragma unroll
    for (int q = 0; q < 4; ++q) {
        Chh[q] = (f32x4){0.f, 0.f, 0.f, 0.f};
        Chl[q] = (f32x4){0.f, 0.f, 0.f, 0.f};
    }
    float s1acc[4] = {0.f, 0.f, 0.f, 0.f};

    const int krow = lane >> 3;        // 0..7
    const int nsub = (lane & 7) * 4;   // 0..28

    for (int rnd = 0; rnd < 4; ++rnd) {
        const int nloc0 = wv * 256 + rnd * 64;   // block-local n base of this wave-round

        // ---- conversion: 64 n x 32 k, fp32 -> u -> bf16 hi/lo in LDS ----
        #pragma unroll
        for (int it = 0; it < 8; ++it) {
            const int k  = krow + 8 * (it & 3);
            const int nn = nsub + 32 * (it >> 2);
            const float4 v4 = *reinterpret_cast<const float4*>(
                vT + (size_t)k * 4096 + p * 1024 + nloc0 + nn);
            const float4 s4 = *reinterpret_cast<const float4*>(&swbuf[nloc0 + nn]);
            const float ux = v4.x * s4.x, uy = v4.y * s4.y;
            const float uz = v4.z * s4.z, uw = v4.w * s4.w;
            const unsigned bx = __float_as_uint(ux), by = __float_as_uint(uy);
            const unsigned bz = __float_as_uint(uz), bw = __float_as_uint(uw);
            const unsigned hi01 = __builtin_amdgcn_perm(by, bx, 0x07060302u);
            const unsigned hi23 = __builtin_amdgcn_perm(bw, bz, 0x07060302u);
            const float lx = ux - __uint_as_float(bx & 0xFFFF0000u);
            const float ly = uy - __uint_as_float(by & 0xFFFF0000u);
            const float lz = uz - __uint_as_float(bz & 0xFFFF0000u);
            const float lw = uw - __uint_as_float(bw & 0xFFFF0000u);
            const unsigned lo01 = __builtin_amdgcn_perm(__float_as_uint(ly), __float_as_uint(lx), 0x07060302u);
            const unsigned lo23 = __builtin_amdgcn_perm(__float_as_uint(lw), __float_as_uint(lz), 0x07060302u);
            const int dwi = k * 36 + (nn >> 1);
            *reinterpret_cast<uint2*>(&ubuf[wv][0][dwi]) = make_uint2(hi01, hi23);
            *reinterpret_cast<uint2*>(&ubuf[wv][1][dwi]) = make_uint2(lo01, lo23);
            // S1 += w*v = sw*u
            s1acc[it & 3] += ux * s4.x + uy * s4.y + uz * s4.z + uw * s4.w;
        }

        // ---- MFMA: 2 chunks of 32 n ----
        #pragma unroll
        for (int c2 = 0; c2 < 2; ++c2) {
            const int ndw = (c2 * 32 + (lane >> 4) * 8) >> 1;
            const int r0 = (lane & 15) * 36 + ndw;
            const int r1 = r0 + 16 * 36;
            const short8 h0 = *reinterpret_cast<const short8*>(&ubuf[wv][0][r0]);
            const short8 h1 = *reinterpret_cast<const short8*>(&ubuf[wv][0][r1]);
            const short8 l0 = *reinterpret_cast<const short8*>(&ubuf[wv][1][r0]);
            const short8 l1 = *reinterpret_cast<const short8*>(&ubuf[wv][1][r1]);
            Chh[0] = __builtin_amdgcn_mfma_f32_16x16x32_bf16(h0, h0, Chh[0], 0, 0, 0);
            Chh[1] = __builtin_amdgcn_mfma_f32_16x16x32_bf16(h0, h1, Chh[1], 0, 0, 0);
            Chh[2] = __builtin_amdgcn_mfma_f32_16x16x32_bf16(h1, h0, Chh[2], 0, 0, 0);
            Chh[3] = __builtin_amdgcn_mfma_f32_16x16x32_bf16(h1, h1, Chh[3], 0, 0, 0);
            Chl[0] = __builtin_amdgcn_mfma_f32_16x16x32_bf16(h0, l0, Chl[0], 0, 0, 0);
            Chl[1] = __builtin_amdgcn_mfma_f32_16x16x32_bf16(h0, l1, Chl[1], 0, 0, 0);
            Chl[2] = __builtin_amdgcn_mfma_f32_16x16x32_bf16(h1, l0, Chl[2], 0, 0, 0);
            Chl[3] = __builtin_amdgcn_mfma_f32_16x16x32_bf16(h1, l1, Chl[3], 0, 0, 0);
        }
    }

    // ---- epilogue scatter: P = hh + 2*hl in MFMA-native lane layout ----
    float* redw = reinterpret_cast<float*>(&ubuf[wv][0][0]);  // 1024 of 2304 dw
    #pragma unroll
    for (int q = 0; q < 4; ++q) {
        #pragma unroll
        for (int r = 0; r < 4; ++r) {
            redw[q * 256 + r * 64 + lane] = Chh[q][r] + 2.0f * Chl[q][r];
        }
    }

    // ---- wave-level Z/count reduce (registers, no LDS) ----
    #pragma unroll
    for (int s = 1; s < 64; s <<= 1) {
        zacc += __shfl_xor(zacc, s);
        cacc += __shfl_xor(cacc, s);
    }

    __syncthreads();   // B1: all conversions + scatters done; swbuf dead
    if (t < 32) s1buf[t] = 0.0f;
    if (lane == 0) { zred[wv] = zacc; zred[4 + wv] = cacc; }
    __syncthreads();   // B2: overlays initialized

    // ---- S1 reduce: 8 consecutive lanes share k ----
    #pragma unroll
    for (int j = 0; j < 4; ++j) {
        float r = s1acc[j];
        r += __shfl_xor(r, 1);
        r += __shfl_xor(r, 2);
        r += __shfl_xor(r, 4);
        if ((lane & 7) == 0) atomicAdd(&s1buf[krow + 8 * j], r);
    }
    __syncthreads();   // B3: s1 complete

    // ---- cross-wave sum + write record ----
    const size_t base = (size_t)(m * 4 + p) * PART_STRIDE;
    float o0 = 0.f, o1 = 0.f, o2 = 0.f, o3 = 0.f;
    #pragma unroll
    for (int ww = 0; ww < 4; ++ww) {
        const float4 x = *reinterpret_cast<const float4*>(
            &reinterpret_cast<float*>(&ubuf[ww][0][0])[t * 4]);
        o0 += x.x; o1 += x.y; o2 += x.z; o3 += x.w;
    }
    *reinterpret_cast<float4*>(&wsout[base + t * 4]) = make_float4(o0, o1, o2, o3);
    if (t == 0) wsout[base + 1056] = zred[0] + zred[1] + zred[2] + zred[3];
    if (t == 1) wsout[base + 1057] = zred[4] + zred[5] + zred[6] + zred[7];
    if (t < 32) wsout[base + 1024 + t] = s1buf[t];
}

// ---------------------------------------------------------------------------
// K3: combine.
//   G = op^T op ; psi = tr(G P)/Z - vbar^T G vbar ; gate count>=2
// Record P is in MFMA-native lane layout: element (a,b) lives at
//   ((a>>4)*2+(b>>4))*256 + (a&3)*64 + ((a>>2)&3)*16 + (b&15)
// Thread t wants (k, l0..l0+3), which is a contiguous aligned float4.
// ---------------------------------------------------------------------------
__global__ __launch_bounds__(256) void combine_kernel(const float* __restrict__ op,
                                                      const float* __restrict__ ws,
                                                      float* __restrict__ out) {
    const int m = blockIdx.x;
    const int t = threadIdx.x;

    __shared__ float omg[32 * 33];
    __shared__ float vbar[32];
    __shared__ float red[256];

    #pragma unroll
    for (int i = 0; i < 4; ++i) {
        const int g = t + 256 * i;
        omg[(g >> 5) * 33 + (g & 31)] = op[(size_t)m * 1024 + g];
    }

    const int k  = t >> 3;
    const int l0 = (t & 7) * 4;
    const int pbase = ((k >> 4) * 2 + (l0 >> 4)) * 256
                    + (k & 3) * 64 + ((k >> 2) & 3) * 16 + (l0 & 15);

    const size_t mb = (size_t)m * 4 * PART_STRIDE;
    float Z = 0.0f, cnt = 0.0f, s1 = 0.0f;
    float s2[4] = {0.f, 0.f, 0.f, 0.f};
    #pragma unroll
    for (int p2 = 0; p2 < 4; ++p2) {
        const size_t bp = mb + (size_t)p2 * PART_STRIDE;
        Z   += ws[bp + 1056];
        cnt += ws[bp + 1057];
        if (t < 32) s1 += ws[bp + 1024 + t];
        const float4 sp = *reinterpret_cast<const float4*>(&ws[bp + pbase]);
        s2[0] += sp.x; s2[1] += sp.y; s2[2] += sp.z; s2[3] += sp.w;
    }
    const float invZ = 1.0f / fmaxf(Z, 1e-30f);
    if (t < 32) vbar[t] = s1 * invZ;
    __syncthreads();

    float G[4] = {0.f, 0.f, 0.f, 0.f};
    #pragma unroll
    for (int i = 0; i < 32; ++i) {
        const float ok = omg[i * 33 + k];
        #pragma unroll
        for (int q = 0; q < 4; ++q) G[q] = fmaf(ok, omg[i * 33 + l0 + q], G[q]);
    }

    const float vk = vbar[k];
    float val = 0.0f;
    #pragma unroll
    for (int q = 0; q < 4; ++q)
        val += G[q] * (s2[q] * invZ - vk * vbar[l0 + q]);

    red[t] = val; __syncthreads();
    #pragma unroll
    for (int s = 128; s > 0; s >>= 1) {
        if (t < s) red[t] += red[t + s];
        __syncthreads();
    }
    if (t == 0) out[m] = (cnt >= 1.5f) ? red[0] : 0.0f;
}

// ---------------------------------------------------------------------------
extern "C" void kernel_launch(void* const* d_in, const int* in_sizes, int n_in,
                              void* d_out, int out_size, void* d_ws, size_t ws_size,
                              hipStream_t stream) {
    const float* W  = (const float*)d_in[0];  // (4096, 256)
    const float* mu = (const float*)d_in[1];  // (4096, 32)
    const float* oc = (const float*)d_in[2];  // (4096, 32, 32)
    const float* op = (const float*)d_in[3];  // (256, 32, 32)
    float* out = (float*)d_out;               // (256,)
    float* ws  = (float*)d_ws;

    prep_kernel<<<2048, 256, 0, stream>>>(W, mu, oc, ws);
    partial_kernel<<<1024, 256, 0, stream>>>(ws + WT_OFF, ws + VT_OFF, ws);
    combine_kernel<<<256, 256, 0, stream>>>(op, ws, out);
}

// Round 4
// 103.842 us; speedup vs baseline: 1.0491x; 1.0491x over previous
//
#include <hip/hip_runtime.h>

// Problem constants (fixed by reference)
constexpr int N_AG = 4096;   // N agents
constexpr int M_CL = 256;    // M clusters
constexpr int KD   = 32;     // K dim
constexpr float WEPS = 1e-6f;

// ws layout (floats)
constexpr int PART_STRIDE = 1088;                 // [P(1024, MFMA-lane layout) | S1(32) | Z | count | pad]
constexpr int PART_SZ = M_CL * 4 * PART_STRIDE;   // 1,114,112
constexpr int VT_OFF  = PART_SZ;                  // vT (32 x 4096) k-major
// ROUND-10: Wt eliminated — partial reads W directly (strided, L2/L3-served).

typedef __attribute__((ext_vector_type(8))) short short8;   // 8 bf16 (4 VGPRs)
typedef __attribute__((ext_vector_type(4))) float f32x4;

__device__ __forceinline__ float rlane(float x, int l) {
    return __int_as_float(__builtin_amdgcn_readlane(__float_as_int(x), l));
}

__device__ __forceinline__ float fast_rcp(float x) {
#if __has_builtin(__builtin_amdgcn_rcpf)
    float r = __builtin_amdgcn_rcpf(x);      // v_rcp_f32 (~1 ulp)
    return r * (2.0f - x * r);               // +1 NR step -> ~2^-29 rel err
#else
    return 1.0f / x;
#endif
}

// ---------------------------------------------------------------------------
// Solve: row-layout forward elimination + back-substitution (R9).
// Lane r (r = lane&31; lanes 32-63 duplicate rows 0-31 so broadcasts stay
// readlane-uniform, zero divergence) holds row r of A + rhs scalar.
// No pivoting: SPD with diag >= 1. Template-recursive so all a[j] indices
// are compile-time (R6 scratch lesson).
// ---------------------------------------------------------------------------
template<int J>
struct FE {
    static __device__ __forceinline__ void run(float (&a)[32], float& rhs,
                                               float& pl, const int rr) {
        const float piv  = rlane(a[J], J);
        const float pinv = fast_rcp(piv);
        if (rr == J) pl = pinv;                       // save for back-sub
        const float f = (rr > J) ? a[J] * pinv : 0.0f; // rows <= J frozen
        #pragma unroll
        for (int j = J + 1; j < 32; ++j) {
            const float rJ = rlane(a[j], J);
            a[j] = fmaf(-f, rJ, a[j]);
        }
        const float rb = rlane(rhs, J);
        rhs = fmaf(-f, rb, rhs);
        FE<J + 1>::run(a, rhs, pl, rr);
    }
};
template<> struct FE<32> {
    static __device__ __forceinline__ void run(float (&)[32], float&, float&, const int) {}
};

template<int J>
struct BS {
    static __device__ __forceinline__ void run(const float (&a)[32], float& rhs,
                                               const float pl, float& xv, const int rr) {
        const float xj = rlane(rhs, J) * rlane(pl, J);  // uniform
        if (rr == J) xv = xj;
        rhs = fmaf(-a[J], xj, rhs);   // corrupts rr>=J lanes: already consumed
        BS<J - 1>::run(a, rhs, pl, xv, rr);
    }
};
template<> struct BS<-1> {
    static __device__ __forceinline__ void run(const float (&)[32], float&,
                                               const float, float&, const int) {}
};

// ---------------------------------------------------------------------------
// K1 (ROUND-10): pure solve, 1024 blocks (W-transpose half deleted — Wt is
// no longer materialized; partial reads W directly). 4 matrices/block,
// 1 wave each, then in-block LDS transpose -> vT (32 x 4096) k-major.
// ---------------------------------------------------------------------------
__global__ __launch_bounds__(256) void solve_kernel(const float* __restrict__ mu,
                                                    const float* __restrict__ oc,
                                                    float* __restrict__ ws) {
    __shared__ float sv[4][32];
    const int t    = threadIdx.x;
    const int lane = t & 63;
    const int wid  = t >> 6;
    const int n0   = blockIdx.x * 4;
    const int idx  = n0 + wid;
    const int rr   = lane & 31;           // lanes 32-63 mirror rows 0-31

    float a[32];
    const float4* src = reinterpret_cast<const float4*>(oc + (size_t)idx * 1024 + rr * 32);
    #pragma unroll
    for (int q = 0; q < 8; ++q) {
        const float4 t4 = src[q];
        a[4 * q + 0] = t4.x; a[4 * q + 1] = t4.y;
        a[4 * q + 2] = t4.z; a[4 * q + 3] = t4.w;
    }
    float rhs = mu[(size_t)idx * 32 + rr];
    float pl = 0.0f, xv = 0.0f;

    FE<0>::run(a, rhs, pl, rr);
    BS<31>::run(a, rhs, pl, xv, rr);

    if (lane < 32) sv[wid][lane] = xv;
    __syncthreads();
    // vT[k][n0..n0+3]: 16B-coalesced per k-row
    if (t < 128) {
        const int k = t >> 2;
        const int j = t & 3;
        ws[VT_OFF + (size_t)k * 4096 + n0 + j] = sv[j][k];
    }
}

// ---------------------------------------------------------------------------
// K2: per (m,p) block, S2 = sum_n w v v^T via u = sqrt(w) v, MFMA
// rank-reduction over n. u split hi/lo bf16 (RTZ).
// ROUND-10 stage-w: read W column m of quarter p DIRECTLY (4 scalar loads,
// stride 1 KB). Each 64B line is shared by 16 consecutive m-blocks -> HBM
// fetch stays ~4 MB (L2/L3 amplify), and the 12 MB Wt materialization
// round-trip (prep W-read + Wt-write + partial Wt-read) is deleted.
// Mask applied inline: masked value for Z/sqrt, raw >= WEPS for count —
// identical semantics to the old Wt contents.
// Epilogue stores P = hh + 2*hl in MFMA-native lane layout (G symmetric ->
// tr(G(hl+hl^T)) = 2 tr(G hl)); bank = lane&31 -> 2-way conflict = free.
// zred/s1buf overlaid on swbuf (dead after main loop) -> LDS 40,960 B
// -> 4 blocks/CU, grid exactly 4x256.
// ---------------------------------------------------------------------------
__global__ __launch_bounds__(256, 4) void partial_kernel(const float* __restrict__ W,
                                                         const float* __restrict__ vT,
                                                         float* __restrict__ wsout) {
    const int m = blockIdx.x >> 2;
    const int p = blockIdx.x & 3;
    const int t = threadIdx.x;
    const int lane = t & 63;
    const int wv   = t >> 6;     // wave id 0..3

    __shared__ unsigned ubuf[4][2][32 * 36];  // [wave][hi/lo][k*36 + n/2] : 36,864 B
    __shared__ float swbuf[1024];             // sqrt(w); dead after main loop: 4,096 B
    float* const s1buf = swbuf;               // overlay [0..31]
    float* const zred  = swbuf + 32;          // overlay [32..39]

    // ---- stage w: direct strided W read, mask, sqrt, Z, count ----
    const int rbase = p * 1024 + t * 4;
    const float w0 = W[(size_t)(rbase + 0) * 256 + m];
    const float w1 = W[(size_t)(rbase + 1) * 256 + m];
    const float w2 = W[(size_t)(rbase + 2) * 256 + m];
    const float w3 = W[(size_t)(rbase + 3) * 256 + m];
    const float m0 = (w0 >= WEPS) ? w0 : 0.0f;
    const float m1 = (w1 >= WEPS) ? w1 : 0.0f;
    const float m2 = (w2 >= WEPS) ? w2 : 0.0f;
    const float m3 = (w3 >= WEPS) ? w3 : 0.0f;
    float zacc = m0 + m1 + m2 + m3;
    float cacc = (w0 >= WEPS ? 1.f : 0.f) + (w1 >= WEPS ? 1.f : 0.f)
               + (w2 >= WEPS ? 1.f : 0.f) + (w3 >= WEPS ? 1.f : 0.f);
    reinterpret_cast<float4*>(swbuf)[t] =
        make_float4(sqrtf(m0), sqrtf(m1), sqrtf(m2), sqrtf(m3));

    f32x4 Chh[4], Chl[4];
    #pragma unroll
    for (int q = 0; q < 4; ++q) {
        Chh[q] = (f32x4){0.f, 0.f, 0.f, 0.f};
        Chl[q] = (f32x4){0.f, 0.f, 0.f, 0.f};
    }
    float s1acc[4] = {0.f, 0.f, 0.f, 0.f};

    const int krow = lane >> 3;        // 0..7
    const int nsub = (lane & 7) * 4;   // 0..28

    for (int rnd = 0; rnd < 4; ++rnd) {
        const int nloc0 = wv * 256 + rnd * 64;   // block-local n base of this wave-round

        // ---- conversion: 64 n x 32 k, fp32 -> u -> bf16 hi/lo in LDS ----
        #pragma unroll
        for (int it = 0; it < 8; ++it) {
            const int k  = krow + 8 * (it & 3);
            const int nn = nsub + 32 * (it >> 2);
            const float4 v4 = *reinterpret_cast<const float4*>(
                vT + (size_t)k * 4096 + p * 1024 + nloc0 + nn);
            const float4 s4 = *reinterpret_cast<const float4*>(&swbuf[nloc0 + nn]);
            const float ux = v4.x * s4.x, uy = v4.y * s4.y;
            const float uz = v4.z * s4.z, uw = v4.w * s4.w;
            const unsigned bx = __float_as_uint(ux), by = __float_as_uint(uy);
            const unsigned bz = __float_as_uint(uz), bw = __float_as_uint(uw);
            const unsigned hi01 = __builtin_amdgcn_perm(by, bx, 0x07060302u);
            const unsigned hi23 = __builtin_amdgcn_perm(bw, bz, 0x07060302u);
            const float lx = ux - __uint_as_float(bx & 0xFFFF0000u);
            const float ly = uy - __uint_as_float(by & 0xFFFF0000u);
            const float lz = uz - __uint_as_float(bz & 0xFFFF0000u);
            const float lw = uw - __uint_as_float(bw & 0xFFFF0000u);
            const unsigned lo01 = __builtin_amdgcn_perm(__float_as_uint(ly), __float_as_uint(lx), 0x07060302u);
            const unsigned lo23 = __builtin_amdgcn_perm(__float_as_uint(lw), __float_as_uint(lz), 0x07060302u);
            const int dwi = k * 36 + (nn >> 1);
            *reinterpret_cast<uint2*>(&ubuf[wv][0][dwi]) = make_uint2(hi01, hi23);
            *reinterpret_cast<uint2*>(&ubuf[wv][1][dwi]) = make_uint2(lo01, lo23);
            // S1 += w*v = sw*u
            s1acc[it & 3] += ux * s4.x + uy * s4.y + uz * s4.z + uw * s4.w;
        }

        // ---- MFMA: 2 chunks of 32 n ----
        #pragma unroll
        for (int c2 = 0; c2 < 2; ++c2) {
            const int ndw = (c2 * 32 + (lane >> 4) * 8) >> 1;
            const int r0 = (lane & 15) * 36 + ndw;
            const int r1 = r0 + 16 * 36;
            const short8 h0 = *reinterpret_cast<const short8*>(&ubuf[wv][0][r0]);
            const short8 h1 = *reinterpret_cast<const short8*>(&ubuf[wv][0][r1]);
            const short8 l0 = *reinterpret_cast<const short8*>(&ubuf[wv][1][r0]);
            const short8 l1 = *reinterpret_cast<const short8*>(&ubuf[wv][1][r1]);
            Chh[0] = __builtin_amdgcn_mfma_f32_16x16x32_bf16(h0, h0, Chh[0], 0, 0, 0);
            Chh[1] = __builtin_amdgcn_mfma_f32_16x16x32_bf16(h0, h1, Chh[1], 0, 0, 0);
            Chh[2] = __builtin_amdgcn_mfma_f32_16x16x32_bf16(h1, h0, Chh[2], 0, 0, 0);
            Chh[3] = __builtin_amdgcn_mfma_f32_16x16x32_bf16(h1, h1, Chh[3], 0, 0, 0);
            Chl[0] = __builtin_amdgcn_mfma_f32_16x16x32_bf16(h0, l0, Chl[0], 0, 0, 0);
            Chl[1] = __builtin_amdgcn_mfma_f32_16x16x32_bf16(h0, l1, Chl[1], 0, 0, 0);
            Chl[2] = __builtin_amdgcn_mfma_f32_16x16x32_bf16(h1, l0, Chl[2], 0, 0, 0);
            Chl[3] = __builtin_amdgcn_mfma_f32_16x16x32_bf16(h1, l1, Chl[3], 0, 0, 0);
        }
    }

    // ---- epilogue scatter: P = hh + 2*hl in MFMA-native lane layout ----
    float* redw = reinterpret_cast<float*>(&ubuf[wv][0][0]);  // 1024 of 2304 dw
    #pragma unroll
    for (int q = 0; q < 4; ++q) {
        #pragma unroll
        for (int r = 0; r < 4; ++r) {
            redw[q * 256 + r * 64 + lane] = Chh[q][r] + 2.0f * Chl[q][r];
        }
    }

    // ---- wave-level Z/count reduce (registers, no LDS) ----
    #pragma unroll
    for (int s = 1; s < 64; s <<= 1) {
        zacc += __shfl_xor(zacc, s);
        cacc += __shfl_xor(cacc, s);
    }

    __syncthreads();   // B1: all conversions + scatters done; swbuf dead
    if (t < 32) s1buf[t] = 0.0f;
    if (lane == 0) { zred[wv] = zacc; zred[4 + wv] = cacc; }
    __syncthreads();   // B2: overlays initialized

    // ---- S1 reduce: 8 consecutive lanes share k ----
    #pragma unroll
    for (int j = 0; j < 4; ++j) {
        float r = s1acc[j];
        r += __shfl_xor(r, 1);
        r += __shfl_xor(r, 2);
        r += __shfl_xor(r, 4);
        if ((lane & 7) == 0) atomicAdd(&s1buf[krow + 8 * j], r);
    }
    __syncthreads();   // B3: s1 complete

    // ---- cross-wave sum + write record ----
    const size_t base = (size_t)(m * 4 + p) * PART_STRIDE;
    float o0 = 0.f, o1 = 0.f, o2 = 0.f, o3 = 0.f;
    #pragma unroll
    for (int ww = 0; ww < 4; ++ww) {
        const float4 x = *reinterpret_cast<const float4*>(
            &reinterpret_cast<float*>(&ubuf[ww][0][0])[t * 4]);
        o0 += x.x; o1 += x.y; o2 += x.z; o3 += x.w;
    }
    *reinterpret_cast<float4*>(&wsout[base + t * 4]) = make_float4(o0, o1, o2, o3);
    if (t == 0) wsout[base + 1056] = zred[0] + zred[1] + zred[2] + zred[3];
    if (t == 1) wsout[base + 1057] = zred[4] + zred[5] + zred[6] + zred[7];
    if (t < 32) wsout[base + 1024 + t] = s1buf[t];
}

// ---------------------------------------------------------------------------
// K3: combine.
//   G = op^T op ; psi = tr(G P)/Z - vbar^T G vbar ; gate count>=2
// Record P is in MFMA-native lane layout: element (a,b) lives at
//   ((a>>4)*2+(b>>4))*256 + (a&3)*64 + ((a>>2)&3)*16 + (b&15)
// Thread t wants (k, l0..l0+3), which is a contiguous aligned float4.
// ---------------------------------------------------------------------------
__global__ __launch_bounds__(256) void combine_kernel(const float* __restrict__ op,
                                                      const float* __restrict__ ws,
                                                      float* __restrict__ out) {
    const int m = blockIdx.x;
    const int t = threadIdx.x;

    __shared__ float omg[32 * 33];
    __shared__ float vbar[32];
    __shared__ float red[256];

    #pragma unroll
    for (int i = 0; i < 4; ++i) {
        const int g = t + 256 * i;
        omg[(g >> 5) * 33 + (g & 31)] = op[(size_t)m * 1024 + g];
    }

    const int k  = t >> 3;
    const int l0 = (t & 7) * 4;
    const int pbase = ((k >> 4) * 2 + (l0 >> 4)) * 256
                    + (k & 3) * 64 + ((k >> 2) & 3) * 16 + (l0 & 15);

    const size_t mb = (size_t)m * 4 * PART_STRIDE;
    float Z = 0.0f, cnt = 0.0f, s1 = 0.0f;
    float s2[4] = {0.f, 0.f, 0.f, 0.f};
    #pragma unroll
    for (int p2 = 0; p2 < 4; ++p2) {
        const size_t bp = mb + (size_t)p2 * PART_STRIDE;
        Z   += ws[bp + 1056];
        cnt += ws[bp + 1057];
        if (t < 32) s1 += ws[bp + 1024 + t];
        const float4 sp = *reinterpret_cast<const float4*>(&ws[bp + pbase]);
        s2[0] += sp.x; s2[1] += sp.y; s2[2] += sp.z; s2[3] += sp.w;
    }
    const float invZ = 1.0f / fmaxf(Z, 1e-30f);
    if (t < 32) vbar[t] = s1 * invZ;
    __syncthreads();

    float G[4] = {0.f, 0.f, 0.f, 0.f};
    #pragma unroll
    for (int i = 0; i < 32; ++i) {
        const float ok = omg[i * 33 + k];
        #pragma unroll
        for (int q = 0; q < 4; ++q) G[q] = fmaf(ok, omg[i * 33 + l0 + q], G[q]);
    }

    const float vk = vbar[k];
    float val = 0.0f;
    #pragma unroll
    for (int q = 0; q < 4; ++q)
        val += G[q] * (s2[q] * invZ - vk * vbar[l0 + q]);

    red[t] = val; __syncthreads();
    #pragma unroll
    for (int s = 128; s > 0; s >>= 1) {
        if (t < s) red[t] += red[t + s];
        __syncthreads();
    }
    if (t == 0) out[m] = (cnt >= 1.5f) ? red[0] : 0.0f;
}

// ---------------------------------------------------------------------------
extern "C" void kernel_launch(void* const* d_in, const int* in_sizes, int n_in,
                              void* d_out, int out_size, void* d_ws, size_t ws_size,
                              hipStream_t stream) {
    const float* W  = (const float*)d_in[0];  // (4096, 256)
    const float* mu = (const float*)d_in[1];  // (4096, 32)
    const float* oc = (const float*)d_in[2];  // (4096, 32, 32)
    const float* op = (const float*)d_in[3];  // (256, 32, 32)
    float* out = (float*)d_out;               // (256,)
    float* ws  = (float*)d_ws;

    solve_kernel<<<1024, 256, 0, stream>>>(mu, oc, ws);
    partial_kernel<<<1024, 256, 0, stream>>>(W, ws + VT_OFF, ws);
    combine_kernel<<<256, 256, 0, stream>>>(op, ws, out);
}

// Round 5
// 102.686 us; speedup vs baseline: 1.0609x; 1.0113x over previous
//
#include <hip/hip_runtime.h>

// Problem constants (fixed by reference)
constexpr int N_AG = 4096;   // N agents
constexpr int M_CL = 256;    // M clusters
constexpr int KD   = 32;     // K dim
constexpr float WEPS = 1e-6f;

// ws layout: only vT (32 x 4096) k-major remains (records eliminated in R11).
constexpr int VT_OFF = 0;

typedef __attribute__((ext_vector_type(8))) short short8;   // 8 bf16 (4 VGPRs)
typedef __attribute__((ext_vector_type(4))) float f32x4;

__device__ __forceinline__ float rlane(float x, int l) {
    return __int_as_float(__builtin_amdgcn_readlane(__float_as_int(x), l));
}

__device__ __forceinline__ float fast_rcp(float x) {
#if __has_builtin(__builtin_amdgcn_rcpf)
    float r = __builtin_amdgcn_rcpf(x);      // v_rcp_f32 (~1 ulp)
    return r * (2.0f - x * r);               // +1 NR step -> ~2^-29 rel err
#else
    return 1.0f / x;
#endif
}

// ---------------------------------------------------------------------------
// Solve: row-layout forward elimination + back-substitution (R9).
// Lane r (r = lane&31; lanes 32-63 duplicate rows 0-31 so broadcasts stay
// readlane-uniform, zero divergence) holds row r of A + rhs scalar.
// No pivoting: SPD with diag >= 1. Template-recursive so all a[j] indices
// are compile-time (R6 scratch lesson).
// ---------------------------------------------------------------------------
template<int J>
struct FE {
    static __device__ __forceinline__ void run(float (&a)[32], float& rhs,
                                               float& pl, const int rr) {
        const float piv  = rlane(a[J], J);
        const float pinv = fast_rcp(piv);
        if (rr == J) pl = pinv;                       // save for back-sub
        const float f = (rr > J) ? a[J] * pinv : 0.0f; // rows <= J frozen
        #pragma unroll
        for (int j = J + 1; j < 32; ++j) {
            const float rJ = rlane(a[j], J);
            a[j] = fmaf(-f, rJ, a[j]);
        }
        const float rb = rlane(rhs, J);
        rhs = fmaf(-f, rb, rhs);
        FE<J + 1>::run(a, rhs, pl, rr);
    }
};
template<> struct FE<32> {
    static __device__ __forceinline__ void run(float (&)[32], float&, float&, const int) {}
};

template<int J>
struct BS {
    static __device__ __forceinline__ void run(const float (&a)[32], float& rhs,
                                               const float pl, float& xv, const int rr) {
        const float xj = rlane(rhs, J) * rlane(pl, J);  // uniform
        if (rr == J) xv = xj;
        rhs = fmaf(-a[J], xj, rhs);   // corrupts rr>=J lanes: already consumed
        BS<J - 1>::run(a, rhs, pl, xv, rr);
    }
};
template<> struct BS<-1> {
    static __device__ __forceinline__ void run(const float (&)[32], float&,
                                               const float, float&, const int) {}
};

// ---------------------------------------------------------------------------
// K1: pure solve, 1024 blocks. 4 matrices/block, 1 wave each, then in-block
// LDS transpose -> vT (32 x 4096) k-major.
// ---------------------------------------------------------------------------
__global__ __launch_bounds__(256) void solve_kernel(const float* __restrict__ mu,
                                                    const float* __restrict__ oc,
                                                    float* __restrict__ ws) {
    __shared__ float sv[4][32];
    const int t    = threadIdx.x;
    const int lane = t & 63;
    const int wid  = t >> 6;
    const int n0   = blockIdx.x * 4;
    const int idx  = n0 + wid;
    const int rr   = lane & 31;           // lanes 32-63 mirror rows 0-31

    float a[32];
    const float4* src = reinterpret_cast<const float4*>(oc + (size_t)idx * 1024 + rr * 32);
    #pragma unroll
    for (int q = 0; q < 8; ++q) {
        const float4 t4 = src[q];
        a[4 * q + 0] = t4.x; a[4 * q + 1] = t4.y;
        a[4 * q + 2] = t4.z; a[4 * q + 3] = t4.w;
    }
    float rhs = mu[(size_t)idx * 32 + rr];
    float pl = 0.0f, xv = 0.0f;

    FE<0>::run(a, rhs, pl, rr);
    BS<31>::run(a, rhs, pl, xv, rr);

    if (lane < 32) sv[wid][lane] = xv;
    __syncthreads();
    // vT[k][n0..n0+3]: 16B-coalesced per k-row
    if (t < 128) {
        const int k = t >> 2;
        const int j = t & 3;
        ws[VT_OFF + (size_t)k * 4096 + n0 + j] = sv[j][k];
    }
}

// ---------------------------------------------------------------------------
// K2 (ROUND-11 mega-fusion): ONE block per m owns all 4096 n -> the partial/
// combine split (9 MB record round-trip + 3rd launch) is eliminated with NO
// cross-block communication (no device fences — the R1 trap).
// 256 blocks x 1024 threads (16 waves, 4/SIMD — occupancy preserved; grid maps
// 1:1 onto 256 CUs). Wave wv owns n in [wv*256, wv*256+256), processed in 8
// rounds of 32 n (halved staging buffer: [2][32k x 20dw]/wave; stride 20 dw =
// 80 B keeps ds_read_b128 16B-aligned, same min-aliasing bank profile).
// LDS = 16*2*640*4 + 16384 = 98,304 B -> 1 block/CU (gfx950 allows >64KB
// static LDS; guide's 8-phase example uses 128 KiB).
// Math identical to R4: u = sqrt(w)v hi/lo bf16 split, S2 = u^T u via MFMA,
// P = hh + 2*hl (G symmetric => tr(G(hl+hl^T)) = 2 tr(G hl)).
// Epilogue: after the 16-way cross-wave LDS sum, thread t holds EXACTLY
// element t of P in MFMA-lane layout, which bijects to (a,b):
//   q=t>>8, r=(t>>6)&3, a=(q>>1)*16+((t>>4)&3)*4+r, b=(q&1)*16+(t&15)
// so each thread computes G_ab = sum_i omg[i,a]*omg[i,b] and its psi term
// locally — P never leaves registers again.
// ---------------------------------------------------------------------------
__global__ __launch_bounds__(1024, 4) void fused_kernel(const float* __restrict__ W,
                                                        const float* __restrict__ vT,
                                                        const float* __restrict__ op,
                                                        float* __restrict__ out) {
    const int m  = blockIdx.x;
    const int t  = threadIdx.x;
    const int lane = t & 63;
    const int wv   = t >> 6;     // wave id 0..15

    __shared__ unsigned ubuf[16][2][640];  // [wave][hi/lo][k*20 + n/2] : 81,920 B
    __shared__ float swbuf[4096];          // sqrt(w); dead after main loop: 16,384 B
    // post-loop overlays inside swbuf:
    float* const s1buf = swbuf;            // [0..31]
    float* const zredL = swbuf + 32;       // [32..47]
    float* const credL = swbuf + 48;       // [48..63]
    float* const omg   = swbuf + 64;       // [64..1119]  32*33
    float* const vbar  = swbuf + 1120;     // [1120..1151]
    float* const red2  = swbuf + 1152;     // [1152..1167]

    // ---- stage w: direct strided W read (column m), mask, sqrt, Z, count ----
    // thread t covers rows 4t..4t+3; wave wv's conversion reads swbuf slice
    // [wv*256, +256) written by its own threads -> wave-private, no barrier.
    const int rbase = t * 4;
    const float w0 = W[(size_t)(rbase + 0) * 256 + m];
    const float w1 = W[(size_t)(rbase + 1) * 256 + m];
    const float w2 = W[(size_t)(rbase + 2) * 256 + m];
    const float w3 = W[(size_t)(rbase + 3) * 256 + m];
    const float m0 = (w0 >= WEPS) ? w0 : 0.0f;
    const float m1 = (w1 >= WEPS) ? w1 : 0.0f;
    const float m2 = (w2 >= WEPS) ? w2 : 0.0f;
    const float m3 = (w3 >= WEPS) ? w3 : 0.0f;
    float zacc = m0 + m1 + m2 + m3;
    float cacc = (w0 >= WEPS ? 1.f : 0.f) + (w1 >= WEPS ? 1.f : 0.f)
               + (w2 >= WEPS ? 1.f : 0.f) + (w3 >= WEPS ? 1.f : 0.f);
    reinterpret_cast<float4*>(swbuf)[t] =
        make_float4(sqrtf(m0), sqrtf(m1), sqrtf(m2), sqrtf(m3));

    f32x4 Chh[4], Chl[4];
    #pragma unroll
    for (int q = 0; q < 4; ++q) {
        Chh[q] = (f32x4){0.f, 0.f, 0.f, 0.f};
        Chl[q] = (f32x4){0.f, 0.f, 0.f, 0.f};
    }
    float s1acc[4] = {0.f, 0.f, 0.f, 0.f};

    const int krow = lane >> 3;        // 0..7
    const int nsub = (lane & 7) * 4;   // 0..28

    for (int rnd = 0; rnd < 8; ++rnd) {
        const int nloc0 = wv * 256 + rnd * 32;   // global n base of this wave-round

        // ---- conversion: 32 n x 32 k, fp32 -> u -> bf16 hi/lo in LDS ----
        #pragma unroll
        for (int it = 0; it < 4; ++it) {
            const int k = krow + 8 * it;
            const float4 v4 = *reinterpret_cast<const float4*>(
                vT + (size_t)k * 4096 + nloc0 + nsub);
            const float4 s4 = *reinterpret_cast<const float4*>(&swbuf[nloc0 + nsub]);
            const float ux = v4.x * s4.x, uy = v4.y * s4.y;
            const float uz = v4.z * s4.z, uw = v4.w * s4.w;
            const unsigned bx = __float_as_uint(ux), by = __float_as_uint(uy);
            const unsigned bz = __float_as_uint(uz), bw = __float_as_uint(uw);
            const unsigned hi01 = __builtin_amdgcn_perm(by, bx, 0x07060302u);
            const unsigned hi23 = __builtin_amdgcn_perm(bw, bz, 0x07060302u);
            const float lx = ux - __uint_as_float(bx & 0xFFFF0000u);
            const float ly = uy - __uint_as_float(by & 0xFFFF0000u);
            const float lz = uz - __uint_as_float(bz & 0xFFFF0000u);
            const float lw = uw - __uint_as_float(bw & 0xFFFF0000u);
            const unsigned lo01 = __builtin_amdgcn_perm(__float_as_uint(ly), __float_as_uint(lx), 0x07060302u);
            const unsigned lo23 = __builtin_amdgcn_perm(__float_as_uint(lw), __float_as_uint(lz), 0x07060302u);
            const int dwi = k * 20 + (nsub >> 1);
            *reinterpret_cast<uint2*>(&ubuf[wv][0][dwi]) = make_uint2(hi01, hi23);
            *reinterpret_cast<uint2*>(&ubuf[wv][1][dwi]) = make_uint2(lo01, lo23);
            // S1 += w*v = sw*u
            s1acc[it] += ux * s4.x + uy * s4.y + uz * s4.z + uw * s4.w;
        }

        // ---- MFMA: one 32-n chunk ----
        const int r0 = (lane & 15) * 20 + ((lane >> 4) << 2);
        const int r1 = r0 + 320;
        const short8 h0 = *reinterpret_cast<const short8*>(&ubuf[wv][0][r0]);
        const short8 h1 = *reinterpret_cast<const short8*>(&ubuf[wv][0][r1]);
        const short8 l0 = *reinterpret_cast<const short8*>(&ubuf[wv][1][r0]);
        const short8 l1 = *reinterpret_cast<const short8*>(&ubuf[wv][1][r1]);
        Chh[0] = __builtin_amdgcn_mfma_f32_16x16x32_bf16(h0, h0, Chh[0], 0, 0, 0);
        Chh[1] = __builtin_amdgcn_mfma_f32_16x16x32_bf16(h0, h1, Chh[1], 0, 0, 0);
        Chh[2] = __builtin_amdgcn_mfma_f32_16x16x32_bf16(h1, h0, Chh[2], 0, 0, 0);
        Chh[3] = __builtin_amdgcn_mfma_f32_16x16x32_bf16(h1, h1, Chh[3], 0, 0, 0);
        Chl[0] = __builtin_amdgcn_mfma_f32_16x16x32_bf16(h0, l0, Chl[0], 0, 0, 0);
        Chl[1] = __builtin_amdgcn_mfma_f32_16x16x32_bf16(h0, l1, Chl[1], 0, 0, 0);
        Chl[2] = __builtin_amdgcn_mfma_f32_16x16x32_bf16(h1, l0, Chl[2], 0, 0, 0);
        Chl[3] = __builtin_amdgcn_mfma_f32_16x16x32_bf16(h1, l1, Chl[3], 0, 0, 0);
    }

    // ---- P scatter: P = hh + 2*hl in MFMA-native lane layout (wave-private) ----
    float* redw = reinterpret_cast<float*>(&ubuf[wv][0][0]);  // 1024 of 1280 dw
    #pragma unroll
    for (int q = 0; q < 4; ++q) {
        #pragma unroll
        for (int r = 0; r < 4; ++r) {
            redw[q * 256 + r * 64 + lane] = Chh[q][r] + 2.0f * Chl[q][r];
        }
    }

    // ---- wave-level Z/count reduce (registers) ----
    #pragma unroll
    for (int s = 1; s < 64; s <<= 1) {
        zacc += __shfl_xor(zacc, s);
        cacc += __shfl_xor(cacc, s);
    }

    __syncthreads();   // B1: all scatters done; swbuf dead -> overlays live

    if (t < 32) s1buf[t] = 0.0f;
    if (lane == 0) { zredL[wv] = zacc; credL[wv] = cacc; }
    omg[(t >> 5) * 33 + (t & 31)] = op[(size_t)m * 1024 + t];

    // ---- cross-wave P sum: thread t accumulates element t over 16 waves ----
    float Ptot = 0.0f;
    const float* ub = reinterpret_cast<const float*>(&ubuf[0][0][0]);
    #pragma unroll
    for (int ww = 0; ww < 16; ++ww) Ptot += ub[ww * 1280 + t];

    __syncthreads();   // B2: s1buf zeroed, omg/zred/cred staged

    // ---- S1 reduce: 8 consecutive lanes share k ----
    #pragma unroll
    for (int j = 0; j < 4; ++j) {
        float r = s1acc[j];
        r += __shfl_xor(r, 1);
        r += __shfl_xor(r, 2);
        r += __shfl_xor(r, 4);
        if ((lane & 7) == 0) atomicAdd(&s1buf[krow + 8 * j], r);
    }
    __syncthreads();   // B3: s1 complete

    float Z = 0.0f, C = 0.0f;
    #pragma unroll
    for (int w = 0; w < 16; ++w) { Z += zredL[w]; C += credL[w]; }
    const float invZ = 1.0f / fmaxf(Z, 1e-30f);
    if (t < 32) vbar[t] = s1buf[t] * invZ;
    __syncthreads();   // B4: vbar ready

    // ---- per-thread combine: (a,b) from the P lane-layout bijection ----
    const int q = t >> 8;
    const int r = (t >> 6) & 3;
    const int a = (q >> 1) * 16 + ((t >> 4) & 3) * 4 + r;
    const int b = (q & 1) * 16 + (t & 15);
    float G = 0.0f;
    #pragma unroll
    for (int i = 0; i < 32; ++i)
        G = fmaf(omg[i * 33 + a], omg[i * 33 + b], G);
    float val = G * (Ptot * invZ - vbar[a] * vbar[b]);

    #pragma unroll
    for (int s = 1; s < 64; s <<= 1) val += __shfl_xor(val, s);
    if (lane == 0) red2[wv] = val;
    __syncthreads();   // B5
    if (t == 0) {
        float acc = 0.0f;
        #pragma unroll
        for (int w = 0; w < 16; ++w) acc += red2[w];
        out[m] = (C >= 1.5f) ? acc : 0.0f;
    }
}

// ---------------------------------------------------------------------------
extern "C" void kernel_launch(void* const* d_in, const int* in_sizes, int n_in,
                              void* d_out, int out_size, void* d_ws, size_t ws_size,
                              hipStream_t stream) {
    const float* W  = (const float*)d_in[0];  // (4096, 256)
    const float* mu = (const float*)d_in[1];  // (4096, 32)
    const float* oc = (const float*)d_in[2];  // (4096, 32, 32)
    const float* op = (const float*)d_in[3];  // (256, 32, 32)
    float* out = (float*)d_out;               // (256,)
    float* ws  = (float*)d_ws;

    solve_kernel<<<1024, 256, 0, stream>>>(mu, oc, ws);
    fused_kernel<<<256, 1024, 0, stream>>>(W, ws + VT_OFF, op, out);
}